// Round 1
// baseline (444.029 us; speedup 1.0000x reference)
//
#include <hip/hip_runtime.h>
#include <hip/hip_bf16.h>

// Problem constants
#define BB 16
#define TT 64
#define NN 2048
#define HH 32
#define DD 16
#define LAG 7

// ---------------------------------------------------------------------------
// Kernel 1: projections (Q, K^T, V^T) + temporal delay-weighted term.
// One thread per (b, n) row. 128 blocks x 256 threads.
// ---------------------------------------------------------------------------
__global__ __launch_bounds__(256) void proj_kernel(
    const float* __restrict__ x, const float* __restrict__ feat,
    const float* __restrict__ dlw,
    const float* __restrict__ Wk, const float* __restrict__ bk,
    const float* __restrict__ Wq, const float* __restrict__ bq,
    const float* __restrict__ Wv, const float* __restrict__ bv,
    float* __restrict__ KT, float* __restrict__ VT,
    float* __restrict__ Qb, float* __restrict__ Wbuf)
{
    const int tid = blockIdx.x * 256 + threadIdx.x;   // 0 .. B*N-1
    const int b = tid >> 11;
    const int n = tid & (NN - 1);

    // load feature row [32]
    float f[HH];
    {
        const float4* fp = (const float4*)(feat + (size_t)tid * HH);
        #pragma unroll
        for (int i = 0; i < 8; ++i) {
            float4 v = fp[i];
            f[4*i+0] = v.x; f[4*i+1] = v.y; f[4*i+2] = v.z; f[4*i+3] = v.w;
        }
    }

    // q, k projections (H=32 -> D=16)
    float qa[DD], ka[DD];
    #pragma unroll
    for (int d = 0; d < DD; ++d) { qa[d] = bq[d]; ka[d] = bk[d]; }
    #pragma unroll
    for (int h = 0; h < HH; ++h) {
        const float fh = f[h];
        #pragma unroll
        for (int d = 0; d < DD; ++d) {
            qa[d] += fh * Wq[h*DD + d];
            ka[d] += fh * Wk[h*DD + d];
        }
    }
    {
        float4* qo = (float4*)(Qb + (size_t)tid * DD);
        #pragma unroll
        for (int i = 0; i < 4; ++i)
            qo[i] = make_float4(qa[4*i], qa[4*i+1], qa[4*i+2], qa[4*i+3]);
    }
    {
        float* kb = KT + (size_t)b * DD * NN;
        #pragma unroll
        for (int d = 0; d < DD; ++d) kb[d*NN + n] = ka[d];   // coalesced per d
    }

    // v projection (H=32 -> 32)
    float va[HH];
    #pragma unroll
    for (int j = 0; j < HH; ++j) va[j] = bv[j];
    #pragma unroll
    for (int h = 0; h < HH; ++h) {
        const float fh = f[h];
        #pragma unroll
        for (int j = 0; j < HH; ++j) va[j] += fh * Wv[h*HH + j];
    }
    {
        float* vb = VT + (size_t)b * HH * NN;
        #pragma unroll
        for (int j = 0; j < HH; ++j) vb[j*NN + n] = va[j];   // coalesced per j
    }

    // temporal delay-weighted sum: softmax(delay_weights) over LAG, reversed lags
    float w[LAG];
    float mx = dlw[0];
    #pragma unroll
    for (int t = 1; t < LAG; ++t) mx = fmaxf(mx, dlw[t]);
    float sum = 0.f;
    #pragma unroll
    for (int t = 0; t < LAG; ++t) { w[t] = __expf(dlw[t] - mx); sum += w[t]; }
    const float inv = 1.f / sum;
    float acc = 0.f;
    #pragma unroll
    for (int t = 0; t < LAG; ++t)
        acc += w[t] * inv * x[(size_t)b * TT * NN + (size_t)(TT - 1 - t) * NN + n];
    Wbuf[tid] = acc;
}

// ---------------------------------------------------------------------------
// Kernel 2: fused affinity + softmax + PV + weighted add + out_proj + LN.
// One wave (64 threads) per (b, n) query row. Two-pass exact softmax;
// scores staged in padded LDS to keep loops rolled without scratch spills.
// ---------------------------------------------------------------------------
__global__ __launch_bounds__(64) void attn_kernel(
    const float* __restrict__ Qb, const float* __restrict__ KT,
    const float* __restrict__ VT, const float* __restrict__ Wbuf,
    const float* __restrict__ adj, const float* __restrict__ awp,
    const float* __restrict__ Wo, const float* __restrict__ bo,
    const float* __restrict__ lng, const float* __restrict__ lnb,
    float* __restrict__ out)
{
    const int rid = blockIdx.x;            // 0 .. B*N-1
    const int b = rid >> 11;
    const int n = rid & (NN - 1);
    const int lane = threadIdx.x;          // 0..63

    __shared__ float s_lds[64][33];        // padded: bank = (lane+it)%32, conflict-free

    const float blend = 1.f / (1.f + __expf(-awp[0]));
    const float c1 = (1.f - blend) * 0.25f;   // folds 1/sqrt(D)=0.25
    const float c2 = blend;

    float q[DD];
    {
        const float4* qp = (const float4*)(Qb + (size_t)rid * DD);
        #pragma unroll
        for (int i = 0; i < 4; ++i) {
            float4 v = qp[i];
            q[4*i+0] = v.x; q[4*i+1] = v.y; q[4*i+2] = v.z; q[4*i+3] = v.w;
        }
    }
    const float* Kb = KT + (size_t)b * DD * NN;
    const float* Vb = VT + (size_t)b * HH * NN;
    const float* arow = adj + (size_t)n * NN;

    // ---- pass 1: scores + max ----
    float mx = -1e30f;
    for (int it = 0; it < NN/64; ++it) {
        const int m = it * 64 + lane;
        float acc = 0.f;
        #pragma unroll
        for (int d = 0; d < DD; ++d) acc += q[d] * Kb[d*NN + m];
        acc = c1 * acc + c2 * arow[m];
        s_lds[lane][it] = acc;
        mx = fmaxf(mx, acc);
    }
    #pragma unroll
    for (int off = 1; off < 64; off <<= 1)
        mx = fmaxf(mx, __shfl_xor(mx, off, 64));

    // ---- pass 2: exp + PV accumulate ----
    float l = 0.f;
    float o[HH];
    #pragma unroll
    for (int h = 0; h < HH; ++h) o[h] = 0.f;
    for (int it = 0; it < NN/64; ++it) {
        const int m = it * 64 + lane;
        const float p = __expf(s_lds[lane][it] - mx);
        l += p;
        #pragma unroll
        for (int h = 0; h < HH; ++h) o[h] += p * Vb[h*NN + m];
    }

    // ---- butterfly reduce across the wave (all lanes end with totals) ----
    #pragma unroll
    for (int off = 1; off < 64; off <<= 1) {
        l += __shfl_xor(l, off, 64);
        #pragma unroll
        for (int h = 0; h < HH; ++h) o[h] += __shfl_xor(o[h], off, 64);
    }

    // ---- epilogue: normalize, add temporal term, Wo GEMM, LayerNorm ----
    const float wgt = Wbuf[rid] * 0.1f;
    const float linv = 1.f / l;
    float prop[HH];
    #pragma unroll
    for (int h = 0; h < HH; ++h) prop[h] = o[h] * linv + wgt;

    if (lane < HH) {
        float acc = bo[lane];
        #pragma unroll
        for (int h = 0; h < HH; ++h) acc += prop[h] * Wo[h*HH + lane];
        float ssum = acc, ssq = acc * acc;
        #pragma unroll
        for (int off = 1; off < HH; off <<= 1) {
            ssum += __shfl_xor(ssum, off, HH);
            ssq  += __shfl_xor(ssq,  off, HH);
        }
        const float mean = ssum * (1.f / HH);
        const float var  = ssq * (1.f / HH) - mean * mean;
        const float rstd = rsqrtf(var + 1e-5f);
        out[(size_t)rid * HH + lane] = (acc - mean) * rstd * lng[lane] + lnb[lane];
    }
}

// ---------------------------------------------------------------------------
extern "C" void kernel_launch(void* const* d_in, const int* in_sizes, int n_in,
                              void* d_out, int out_size, void* d_ws, size_t ws_size,
                              hipStream_t stream)
{
    const float* x    = (const float*)d_in[0];
    const float* feat = (const float*)d_in[1];
    const float* adj  = (const float*)d_in[2];
    const float* dlw  = (const float*)d_in[3];
    const float* aw   = (const float*)d_in[4];
    const float* Wk   = (const float*)d_in[5];
    const float* bk   = (const float*)d_in[6];
    const float* Wq   = (const float*)d_in[7];
    const float* bq   = (const float*)d_in[8];
    const float* Wv   = (const float*)d_in[9];
    const float* bv   = (const float*)d_in[10];
    const float* Wo   = (const float*)d_in[11];
    const float* bo   = (const float*)d_in[12];
    const float* lng  = (const float*)d_in[13];
    const float* lnb  = (const float*)d_in[14];

    float* ws = (float*)d_ws;
    float* KT = ws;                          // B*16*N = 524288 floats
    float* VT = ws + 524288;                 // B*32*N = 1048576 floats
    float* Qb = ws + 1572864;                // B*N*16 = 524288 floats
    float* Wb = ws + 2097152;                // B*N    = 32768 floats
    float* out = (float*)d_out;

    proj_kernel<<<(BB*NN)/256, 256, 0, stream>>>(x, feat, dlw, Wk, bk, Wq, bq,
                                                 Wv, bv, KT, VT, Qb, Wb);
    attn_kernel<<<BB*NN, 64, 0, stream>>>(Qb, KT, VT, Wb, adj, aw,
                                          Wo, bo, lng, lnb, out);
}

// Round 2
// 103.907 us; speedup vs baseline: 4.2733x; 4.2733x over previous
//
#include <hip/hip_runtime.h>
#include <hip/hip_bf16.h>
#include <hip/hip_fp16.h>

// Problem constants
#define BB 16
#define TT 64
#define NN 2048
#define HH 32
#define DD 16
#define LAG 7
#define KT 128

typedef _Float16 h16;
typedef __attribute__((ext_vector_type(8))) _Float16 hfrag;
typedef __attribute__((ext_vector_type(4))) float f32x4;

// ---------------------------------------------------------------------------
// Kernel 1: projections -> fp16 Q,K (row-major [b][n][16]), V^T ([b][h][n]),
// plus temporal delay-weighted term (f32). One thread per (b,n).
// ---------------------------------------------------------------------------
__global__ __launch_bounds__(256) void proj_kernel(
    const float* __restrict__ x, const float* __restrict__ feat,
    const float* __restrict__ dlw,
    const float* __restrict__ Wk, const float* __restrict__ bk,
    const float* __restrict__ Wq, const float* __restrict__ bq,
    const float* __restrict__ Wv, const float* __restrict__ bv,
    h16* __restrict__ Qh, h16* __restrict__ Kh, h16* __restrict__ VTh,
    float* __restrict__ Wbuf)
{
    const int tid = blockIdx.x * 256 + threadIdx.x;   // 0 .. B*N-1
    const int b = tid >> 11;
    const int n = tid & (NN - 1);

    float f[HH];
    {
        const float4* fp = (const float4*)(feat + (size_t)tid * HH);
        #pragma unroll
        for (int i = 0; i < 8; ++i) {
            float4 v = fp[i];
            f[4*i+0] = v.x; f[4*i+1] = v.y; f[4*i+2] = v.z; f[4*i+3] = v.w;
        }
    }

    // q, k projections (H=32 -> D=16)
    float qa[DD], ka[DD];
    #pragma unroll
    for (int d = 0; d < DD; ++d) { qa[d] = bq[d]; ka[d] = bk[d]; }
    #pragma unroll
    for (int h = 0; h < HH; ++h) {
        const float fh = f[h];
        #pragma unroll
        for (int d = 0; d < DD; ++d) {
            qa[d] += fh * Wq[h*DD + d];
            ka[d] += fh * Wk[h*DD + d];
        }
    }
    {
        hfrag q0, q1, k0, k1;
        #pragma unroll
        for (int i = 0; i < 8; ++i) {
            q0[i] = (h16)qa[i];   q1[i] = (h16)qa[8+i];
            k0[i] = (h16)ka[i];   k1[i] = (h16)ka[8+i];
        }
        *(hfrag*)(Qh + (size_t)tid * DD)     = q0;
        *(hfrag*)(Qh + (size_t)tid * DD + 8) = q1;
        *(hfrag*)(Kh + (size_t)tid * DD)     = k0;
        *(hfrag*)(Kh + (size_t)tid * DD + 8) = k1;
    }

    // v projection (H=32 -> 32), stored transposed [b][h][n]
    float va[HH];
    #pragma unroll
    for (int j = 0; j < HH; ++j) va[j] = bv[j];
    #pragma unroll
    for (int h = 0; h < HH; ++h) {
        const float fh = f[h];
        #pragma unroll
        for (int j = 0; j < HH; ++j) va[j] += fh * Wv[h*HH + j];
    }
    {
        h16* vb = VTh + (size_t)b * HH * NN;
        #pragma unroll
        for (int j = 0; j < HH; ++j) vb[(size_t)j*NN + n] = (h16)va[j];
    }

    // temporal delay-weighted sum
    float w[LAG];
    float mx = dlw[0];
    #pragma unroll
    for (int t = 1; t < LAG; ++t) mx = fmaxf(mx, dlw[t]);
    float sum = 0.f;
    #pragma unroll
    for (int t = 0; t < LAG; ++t) { w[t] = __expf(dlw[t] - mx); sum += w[t]; }
    const float inv = 1.f / sum;
    float acc = 0.f;
    #pragma unroll
    for (int t = 0; t < LAG; ++t)
        acc += w[t] * inv * x[(size_t)b * TT * NN + (size_t)(TT - 1 - t) * NN + n];
    Wbuf[tid] = acc;
}

// ---------------------------------------------------------------------------
// Kernel 2: flash-style fused affinity+softmax+PV+out_proj+LN with MFMA.
// Grid: 128 q-tiles x 4 batch-groups. Block: 4 waves; wave w = batch bg*4+w,
// 16 query rows. Online softmax over 16 key-tiles of 128.
// MFMA 16x16x32 fp16; D=16 zero-padded to K=32.
// C-layout (m89): col = lane&15, row = (lane>>4)*4 + reg.
// A/B-layout: row/col = lane&15, k = (lane>>4)*8 + j  (16B contiguous loads).
// ---------------------------------------------------------------------------
__global__ __launch_bounds__(256) void attn_kernel(
    const h16* __restrict__ Qh, const h16* __restrict__ Kh,
    const h16* __restrict__ VTh, const float* __restrict__ Wbuf,
    const float* __restrict__ adj, const float* __restrict__ awp,
    const float* __restrict__ Wo, const float* __restrict__ bo,
    const float* __restrict__ lng, const float* __restrict__ lnb,
    float* __restrict__ out)
{
    const int qt   = blockIdx.x >> 2;        // 0..127
    const int bg   = blockIdx.x & 3;         // 0..3
    const int wave = threadIdx.x >> 6;       // 0..3
    const int lane = threadIdx.x & 63;
    const int b    = bg * 4 + wave;
    const int q0r  = qt * 16;
    const int l = lane & 15, g = lane >> 4;

    __shared__ __attribute__((aligned(16))) h16 Pl_all[4][16][136]; // pad: 272B rows, 16B-aligned
    __shared__ float prop_all[4][16][33];
    h16 (* __restrict__ Pl)[136] = Pl_all[wave];
    float (* __restrict__ prop)[33] = prop_all[wave];

    const float blendv = 1.f / (1.f + __expf(-awp[0]));
    const float c1 = (1.f - blendv) * 0.25f;     // folds 1/sqrt(D)
    const float c2 = blendv;

    const h16* Qb = Qh + (size_t)b * NN * DD;
    const h16* Kb = Kh + (size_t)b * NN * DD;
    const h16* Vb = VTh + (size_t)b * HH * NN;

    const hfrag hz = {(h16)0,(h16)0,(h16)0,(h16)0,(h16)0,(h16)0,(h16)0,(h16)0};
    const f32x4 zero4 = {0.f, 0.f, 0.f, 0.f};

    // Q A-fragment: row = l, k(d) = g*8+j ; d>=16 is zero padding
    hfrag qf = hz;
    if (g < 2) qf = *(const hfrag*)(Qb + (size_t)(q0r + l) * DD + g * 8);

    f32x4 o0 = zero4, o1 = zero4;
    float m_run[4], l_run[4];
    #pragma unroll
    for (int r = 0; r < 4; ++r) { m_run[r] = -1e30f; l_run[r] = 0.f; }

    for (int kt = 0; kt < NN; kt += KT) {
        __syncthreads();   // lockstep waves: shared adj tile stays L1-hot

        // ---- S = Q K^T for 8 column tiles ----
        f32x4 s[8];
        #pragma unroll
        for (int c = 0; c < 8; ++c) {
            hfrag kf = hz;
            if (g < 2) kf = *(const hfrag*)(Kb + (size_t)(kt + c*16 + l) * DD + g * 8);
            s[c] = __builtin_amdgcn_mfma_f32_16x16x32_f16(qf, kf, zero4, 0, 0, 0);
        }

        // ---- aff = c1*s + c2*adj, per-row running max ----
        float mx[4];
        #pragma unroll
        for (int r = 0; r < 4; ++r) mx[r] = m_run[r];
        #pragma unroll
        for (int c = 0; c < 8; ++c) {
            #pragma unroll
            for (int r = 0; r < 4; ++r) {
                const float a = adj[(size_t)(q0r + g*4 + r) * NN + (kt + c*16 + l)];
                const float v = fmaf(c2, a, c1 * s[c][r]);
                s[c][r] = v;
                mx[r] = fmaxf(mx[r], v);
            }
        }
        #pragma unroll
        for (int r = 0; r < 4; ++r) {
            #pragma unroll
            for (int off = 1; off < 16; off <<= 1)
                mx[r] = fmaxf(mx[r], __shfl_xor(mx[r], off, 64));
        }

        // ---- rescale running state ----
        #pragma unroll
        for (int r = 0; r < 4; ++r) {
            const float alpha = __expf(m_run[r] - mx[r]);
            m_run[r] = mx[r];
            l_run[r] *= alpha;
            o0[r] *= alpha;
            o1[r] *= alpha;
        }

        // ---- P = exp(aff - m), stash to LDS (C-layout -> A-layout transpose) ----
        #pragma unroll
        for (int c = 0; c < 8; ++c) {
            #pragma unroll
            for (int r = 0; r < 4; ++r) {
                const float p = __expf(s[c][r] - m_run[r]);
                l_run[r] += p;   // per-lane partial (this lane's columns); reduced at end
                Pl[g*4 + r][c*16 + l] = (h16)p;
            }
        }

        // ---- O += P @ V  (4 chained K=32 chunks, 2 output h-tiles) ----
        #pragma unroll
        for (int ch = 0; ch < 4; ++ch) {
            const hfrag pa = *(const hfrag*)(&Pl[l][ch*32 + g*8]);
            const hfrag v0 = *(const hfrag*)(Vb + (size_t)l        * NN + kt + ch*32 + g*8);
            const hfrag v1 = *(const hfrag*)(Vb + (size_t)(16 + l) * NN + kt + ch*32 + g*8);
            o0 = __builtin_amdgcn_mfma_f32_16x16x32_f16(pa, v0, o0, 0, 0, 0);
            o1 = __builtin_amdgcn_mfma_f32_16x16x32_f16(pa, v1, o1, 0, 0, 0);
        }
    }

    // ---- finalize row sums (reduce partials across the 16 lanes of each group) ----
    #pragma unroll
    for (int r = 0; r < 4; ++r) {
        #pragma unroll
        for (int off = 1; off < 16; off <<= 1)
            l_run[r] += __shfl_xor(l_run[r], off, 64);
    }

    // ---- prop = O/l + 0.1*temporal, staged to LDS for the epilogue ----
    #pragma unroll
    for (int r = 0; r < 4; ++r) {
        const float wgt = Wbuf[b * NN + q0r + g*4 + r] * 0.1f;
        const float inv = 1.f / l_run[r];
        prop[g*4 + r][l]      = fmaf(o0[r], inv, wgt);
        prop[g*4 + r][16 + l] = fmaf(o1[r], inv, wgt);
    }

    // ---- out_proj + LayerNorm: 4 lanes per row, 8 outputs per lane ----
    const int row = lane >> 2;     // 0..15
    const int jg  = lane & 3;      // 0..3
    float pr[HH];
    #pragma unroll
    for (int h = 0; h < HH; ++h) pr[h] = prop[row][h];

    float acc[8];
    #pragma unroll
    for (int j = 0; j < 8; ++j) acc[j] = bo[jg*8 + j];
    #pragma unroll
    for (int h = 0; h < HH; ++h) {
        #pragma unroll
        for (int j = 0; j < 8; ++j)
            acc[j] = fmaf(pr[h], Wo[h*HH + jg*8 + j], acc[j]);
    }

    float ss = 0.f, sq = 0.f;
    #pragma unroll
    for (int j = 0; j < 8; ++j) { ss += acc[j]; sq += acc[j]*acc[j]; }
    ss += __shfl_xor(ss, 1, 64); ss += __shfl_xor(ss, 2, 64);
    sq += __shfl_xor(sq, 1, 64); sq += __shfl_xor(sq, 2, 64);
    const float mean = ss * (1.f / HH);
    const float var  = sq * (1.f / HH) - mean * mean;
    const float rstd = rsqrtf(var + 1e-5f);

    float res[8];
    #pragma unroll
    for (int j = 0; j < 8; ++j)
        res[j] = (acc[j] - mean) * rstd * lng[jg*8 + j] + lnb[jg*8 + j];

    float* op = out + ((size_t)b * NN + q0r + row) * HH + jg * 8;
    *(float4*)(op)     = make_float4(res[0], res[1], res[2], res[3]);
    *(float4*)(op + 4) = make_float4(res[4], res[5], res[6], res[7]);
}

// ---------------------------------------------------------------------------
extern "C" void kernel_launch(void* const* d_in, const int* in_sizes, int n_in,
                              void* d_out, int out_size, void* d_ws, size_t ws_size,
                              hipStream_t stream)
{
    const float* x    = (const float*)d_in[0];
    const float* feat = (const float*)d_in[1];
    const float* adj  = (const float*)d_in[2];
    const float* dlw  = (const float*)d_in[3];
    const float* aw   = (const float*)d_in[4];
    const float* Wk   = (const float*)d_in[5];
    const float* bk   = (const float*)d_in[6];
    const float* Wq   = (const float*)d_in[7];
    const float* bq   = (const float*)d_in[8];
    const float* Wv   = (const float*)d_in[9];
    const float* bv   = (const float*)d_in[10];
    const float* Wo   = (const float*)d_in[11];
    const float* bo   = (const float*)d_in[12];
    const float* lng  = (const float*)d_in[13];
    const float* lnb  = (const float*)d_in[14];

    h16* Qh  = (h16*)d_ws;                   // B*N*16 = 524288 h16
    h16* Kh  = Qh + 524288;                  // 524288 h16
    h16* VTh = Kh + 524288;                  // B*32*N = 1048576 h16
    float* Wb = (float*)(VTh + 1048576);     // B*N = 32768 f32
    float* out = (float*)d_out;

    proj_kernel<<<(BB*NN)/256, 256, 0, stream>>>(x, feat, dlw, Wk, bk, Wq, bq,
                                                 Wv, bv, Qh, Kh, VTh, Wb);
    attn_kernel<<<512, 256, 0, stream>>>(Qh, Kh, VTh, Wb, adj, aw,
                                         Wo, bo, lng, lnb, out);
}

// Round 3
// 87.608 us; speedup vs baseline: 5.0684x; 1.1860x over previous
//
#include <hip/hip_runtime.h>
#include <hip/hip_bf16.h>
#include <hip/hip_fp16.h>

// Problem constants
#define BB 16
#define TT 64
#define NN 2048
#define HH 32
#define DD 16
#define LAG 7
#define KTILE 128
#define NSPLIT 4
#define KSPLIT (NN / NSPLIT)   // 512 keys per block
#define PSTRIDE 36             // floats per (row,split) partial record

typedef _Float16 h16;
typedef __attribute__((ext_vector_type(8))) _Float16 hfrag;
typedef __attribute__((ext_vector_type(4))) float f32x4;

// ---------------------------------------------------------------------------
// Kernel 1: projections -> fp16 Q,K (row-major [b][n][16]), V^T ([b][h][n]),
// plus temporal delay-weighted term (f32). One thread per (b,n).
// Weights staged in LDS (broadcast reads are conflict-free).
// ---------------------------------------------------------------------------
__global__ __launch_bounds__(256) void proj_kernel(
    const float* __restrict__ x, const float* __restrict__ feat,
    const float* __restrict__ dlw,
    const float* __restrict__ Wk, const float* __restrict__ bk,
    const float* __restrict__ Wq, const float* __restrict__ bq,
    const float* __restrict__ Wv, const float* __restrict__ bv,
    h16* __restrict__ Qh, h16* __restrict__ Kh, h16* __restrict__ VTh,
    float* __restrict__ Wbuf)
{
    __shared__ float sWk[HH*DD], sWq[HH*DD], sWv[HH*HH];
    for (int i = threadIdx.x; i < HH*DD; i += 256) { sWk[i] = Wk[i]; sWq[i] = Wq[i]; }
    for (int i = threadIdx.x; i < HH*HH; i += 256) sWv[i] = Wv[i];
    __syncthreads();

    const int tid = blockIdx.x * 256 + threadIdx.x;   // 0 .. B*N-1
    const int b = tid >> 11;
    const int n = tid & (NN - 1);

    float f[HH];
    {
        const float4* fp = (const float4*)(feat + (size_t)tid * HH);
        #pragma unroll
        for (int i = 0; i < 8; ++i) {
            float4 v = fp[i];
            f[4*i+0] = v.x; f[4*i+1] = v.y; f[4*i+2] = v.z; f[4*i+3] = v.w;
        }
    }

    // q, k projections (H=32 -> D=16)
    float qa[DD], ka[DD];
    #pragma unroll
    for (int d = 0; d < DD; ++d) { qa[d] = bq[d]; ka[d] = bk[d]; }
    #pragma unroll
    for (int h = 0; h < HH; ++h) {
        const float fh = f[h];
        #pragma unroll
        for (int d = 0; d < DD; ++d) {
            qa[d] += fh * sWq[h*DD + d];
            ka[d] += fh * sWk[h*DD + d];
        }
    }
    {
        hfrag q0, q1, k0, k1;
        #pragma unroll
        for (int i = 0; i < 8; ++i) {
            q0[i] = (h16)qa[i];   q1[i] = (h16)qa[8+i];
            k0[i] = (h16)ka[i];   k1[i] = (h16)ka[8+i];
        }
        *(hfrag*)(Qh + (size_t)tid * DD)     = q0;
        *(hfrag*)(Qh + (size_t)tid * DD + 8) = q1;
        *(hfrag*)(Kh + (size_t)tid * DD)     = k0;
        *(hfrag*)(Kh + (size_t)tid * DD + 8) = k1;
    }

    // v projection (H=32 -> 32), stored transposed [b][h][n]
    float va[HH];
    #pragma unroll
    for (int j = 0; j < HH; ++j) va[j] = bv[j];
    #pragma unroll
    for (int h = 0; h < HH; ++h) {
        const float fh = f[h];
        #pragma unroll
        for (int j = 0; j < HH; ++j) va[j] += fh * sWv[h*HH + j];
    }
    {
        h16* vb = VTh + (size_t)b * HH * NN;
        #pragma unroll
        for (int j = 0; j < HH; ++j) vb[(size_t)j*NN + n] = (h16)va[j];
    }

    // temporal delay-weighted sum
    float w[LAG];
    float mx = dlw[0];
    #pragma unroll
    for (int t = 1; t < LAG; ++t) mx = fmaxf(mx, dlw[t]);
    float sum = 0.f;
    #pragma unroll
    for (int t = 0; t < LAG; ++t) { w[t] = __expf(dlw[t] - mx); sum += w[t]; }
    const float inv = 1.f / sum;
    float acc = 0.f;
    #pragma unroll
    for (int t = 0; t < LAG; ++t)
        acc += w[t] * inv * x[(size_t)b * TT * NN + (size_t)(TT - 1 - t) * NN + n];
    Wbuf[tid] = acc;
}

// ---------------------------------------------------------------------------
// Kernel 2: split-K flash attention partial. Grid: 128 qt x 4 bg x 4 split.
// Block: 4 waves; wave w handles batch bg*4+w, 16 q-rows, 512 keys.
// No __syncthreads (no cross-wave state). Writes (m, l, o[32]) partials.
// MFMA 16x16x32 fp16; C-layout: col=lane&15, row=(lane>>4)*4+reg.
// ---------------------------------------------------------------------------
__global__ __launch_bounds__(256) void attn_kernel(
    const h16* __restrict__ Qh, const h16* __restrict__ Kh,
    const h16* __restrict__ VTh, const float* __restrict__ adj,
    const float* __restrict__ awp, float* __restrict__ part)
{
    const int id    = blockIdx.x;
    const int qt    = id >> 4;           // 0..127
    const int bg    = (id >> 2) & 3;     // 0..3
    const int split = id & 3;            // 0..3
    const int wave  = threadIdx.x >> 6;
    const int lane  = threadIdx.x & 63;
    const int b     = bg * 4 + wave;
    const int q0r   = qt * 16;
    const int l = lane & 15, g = lane >> 4;

    __shared__ __attribute__((aligned(16))) h16 Pl_all[4][16][136];
    h16 (* __restrict__ Pl)[136] = Pl_all[wave];

    const float blendv = 1.f / (1.f + __expf(-awp[0]));
    const float c1 = (1.f - blendv) * 0.25f;     // folds 1/sqrt(D)
    const float c2 = blendv;

    const h16* Qb = Qh + (size_t)b * NN * DD;
    const h16* Kb = Kh + (size_t)b * NN * DD;
    const h16* Vb = VTh + (size_t)b * HH * NN;

    const hfrag hz = {(h16)0,(h16)0,(h16)0,(h16)0,(h16)0,(h16)0,(h16)0,(h16)0};
    const f32x4 zero4 = {0.f, 0.f, 0.f, 0.f};

    // Q A-fragment: row = l, k(d) = g*8+j ; d>=16 zero padding
    hfrag qf = hz;
    if (g < 2) qf = *(const hfrag*)(Qb + (size_t)(q0r + l) * DD + g * 8);

    f32x4 o0 = zero4, o1 = zero4;
    float m_run[4], l_run[4];
    #pragma unroll
    for (int r = 0; r < 4; ++r) { m_run[r] = -1e30f; l_run[r] = 0.f; }

    const int k0 = split * KSPLIT;
    for (int kt = k0; kt < k0 + KSPLIT; kt += KTILE) {
        // ---- S = Q K^T for 8 column tiles ----
        f32x4 s[8];
        #pragma unroll
        for (int c = 0; c < 8; ++c) {
            hfrag kf = hz;
            if (g < 2) kf = *(const hfrag*)(Kb + (size_t)(kt + c*16 + l) * DD + g * 8);
            s[c] = __builtin_amdgcn_mfma_f32_16x16x32_f16(qf, kf, zero4, 0, 0, 0);
        }

        // ---- aff = c1*s + c2*adj, per-row running max ----
        float mx[4];
        #pragma unroll
        for (int r = 0; r < 4; ++r) mx[r] = m_run[r];
        #pragma unroll
        for (int c = 0; c < 8; ++c) {
            #pragma unroll
            for (int r = 0; r < 4; ++r) {
                const float a = adj[(size_t)(q0r + g*4 + r) * NN + (kt + c*16 + l)];
                const float v = fmaf(c2, a, c1 * s[c][r]);
                s[c][r] = v;
                mx[r] = fmaxf(mx[r], v);
            }
        }
        #pragma unroll
        for (int r = 0; r < 4; ++r) {
            #pragma unroll
            for (int off = 1; off < 16; off <<= 1)
                mx[r] = fmaxf(mx[r], __shfl_xor(mx[r], off, 64));
        }

        // ---- rescale running state ----
        #pragma unroll
        for (int r = 0; r < 4; ++r) {
            const float alpha = __expf(m_run[r] - mx[r]);
            m_run[r] = mx[r];
            l_run[r] *= alpha;
            o0[r] *= alpha;
            o1[r] *= alpha;
        }

        // ---- P = exp(aff - m), stash to LDS (C-layout -> A-layout) ----
        #pragma unroll
        for (int c = 0; c < 8; ++c) {
            #pragma unroll
            for (int r = 0; r < 4; ++r) {
                const float p = __expf(s[c][r] - m_run[r]);
                l_run[r] += p;   // per-lane partial; reduced at the end
                Pl[g*4 + r][c*16 + l] = (h16)p;
            }
        }

        // ---- O += P @ V ----
        #pragma unroll
        for (int ch = 0; ch < 4; ++ch) {
            const hfrag pa = *(const hfrag*)(&Pl[l][ch*32 + g*8]);
            const hfrag v0 = *(const hfrag*)(Vb + (size_t)l        * NN + kt + ch*32 + g*8);
            const hfrag v1 = *(const hfrag*)(Vb + (size_t)(16 + l) * NN + kt + ch*32 + g*8);
            o0 = __builtin_amdgcn_mfma_f32_16x16x32_f16(pa, v0, o0, 0, 0, 0);
            o1 = __builtin_amdgcn_mfma_f32_16x16x32_f16(pa, v1, o1, 0, 0, 0);
        }
    }

    // ---- reduce l partials across the 16 lanes of each group ----
    #pragma unroll
    for (int r = 0; r < 4; ++r) {
        #pragma unroll
        for (int off = 1; off < 16; off <<= 1)
            l_run[r] += __shfl_xor(l_run[r], off, 64);
    }

    // ---- write partial records: [row][split] -> {o[32], m, l} ----
    #pragma unroll
    for (int r = 0; r < 4; ++r) {
        float* rp = part + ((size_t)(b * NN + q0r + g*4 + r) * NSPLIT + split) * PSTRIDE;
        rp[l]      = o0[r];
        rp[16 + l] = o1[r];
        if (l == 0) { rp[32] = m_run[r]; rp[33] = l_run[r]; }
    }
}

// ---------------------------------------------------------------------------
// Kernel 3: combine 4 split partials (log-sum-exp) + temporal add +
// out_proj + LayerNorm. 4 lanes per row; lane jg loads split jg and
// computes output columns jg*8..jg*8+7.
// ---------------------------------------------------------------------------
__global__ __launch_bounds__(256) void combine_kernel(
    const float* __restrict__ part, const float* __restrict__ Wbuf,
    const float* __restrict__ Wo, const float* __restrict__ bo,
    const float* __restrict__ lng, const float* __restrict__ lnb,
    float* __restrict__ out)
{
    __shared__ float sWo[HH*HH];
    __shared__ float sbo[HH], sg[HH], sb[HH];
    for (int i = threadIdx.x; i < HH*HH; i += 256) sWo[i] = Wo[i];
    if (threadIdx.x < HH) {
        sbo[threadIdx.x] = bo[threadIdx.x];
        sg[threadIdx.x]  = lng[threadIdx.x];
        sb[threadIdx.x]  = lnb[threadIdx.x];
    }
    __syncthreads();

    const int rid = blockIdx.x * 64 + (threadIdx.x >> 2);  // 0..B*N-1
    const int jg  = threadIdx.x & 3;

    const float* rp = part + ((size_t)rid * NSPLIT + jg) * PSTRIDE;
    float o[HH];
    #pragma unroll
    for (int i = 0; i < 8; ++i) {
        float4 v = *(const float4*)(rp + i*4);
        o[4*i+0] = v.x; o[4*i+1] = v.y; o[4*i+2] = v.z; o[4*i+3] = v.w;
    }
    const float m_j = rp[32];
    const float l_j = rp[33];

    // global max / sum across the 4 splits (width-4 butterflies)
    float m = m_j;
    m = fmaxf(m, __shfl_xor(m, 1, 64));
    m = fmaxf(m, __shfl_xor(m, 2, 64));
    const float alpha = __expf(m_j - m);
    float lsum = l_j * alpha;
    lsum += __shfl_xor(lsum, 1, 64);
    lsum += __shfl_xor(lsum, 2, 64);

    #pragma unroll
    for (int c = 0; c < HH; ++c) o[c] *= alpha;
    #pragma unroll
    for (int c = 0; c < HH; ++c) {
        o[c] += __shfl_xor(o[c], 1, 64);
        o[c] += __shfl_xor(o[c], 2, 64);
    }

    const float wgt = Wbuf[rid] * 0.1f;
    const float inv = 1.f / lsum;
    float pr[HH];
    #pragma unroll
    for (int c = 0; c < HH; ++c) pr[c] = fmaf(o[c], inv, wgt);

    // Wo GEMM: 8 output columns per lane
    float acc[8];
    #pragma unroll
    for (int j = 0; j < 8; ++j) acc[j] = sbo[jg*8 + j];
    #pragma unroll
    for (int h = 0; h < HH; ++h) {
        #pragma unroll
        for (int j = 0; j < 8; ++j)
            acc[j] = fmaf(pr[h], sWo[h*HH + jg*8 + j], acc[j]);
    }

    // LayerNorm across the 4 lanes (32 values)
    float ss = 0.f, sq = 0.f;
    #pragma unroll
    for (int j = 0; j < 8; ++j) { ss += acc[j]; sq += acc[j]*acc[j]; }
    ss += __shfl_xor(ss, 1, 64); ss += __shfl_xor(ss, 2, 64);
    sq += __shfl_xor(sq, 1, 64); sq += __shfl_xor(sq, 2, 64);
    const float mean = ss * (1.f / HH);
    const float var  = sq * (1.f / HH) - mean * mean;
    const float rstd = rsqrtf(var + 1e-5f);

    float res[8];
    #pragma unroll
    for (int j = 0; j < 8; ++j)
        res[j] = (acc[j] - mean) * rstd * sg[jg*8 + j] + sb[jg*8 + j];

    float* op = out + (size_t)rid * HH + jg * 8;
    *(float4*)(op)     = make_float4(res[0], res[1], res[2], res[3]);
    *(float4*)(op + 4) = make_float4(res[4], res[5], res[6], res[7]);
}

// ---------------------------------------------------------------------------
extern "C" void kernel_launch(void* const* d_in, const int* in_sizes, int n_in,
                              void* d_out, int out_size, void* d_ws, size_t ws_size,
                              hipStream_t stream)
{
    const float* x    = (const float*)d_in[0];
    const float* feat = (const float*)d_in[1];
    const float* adj  = (const float*)d_in[2];
    const float* dlw  = (const float*)d_in[3];
    const float* aw   = (const float*)d_in[4];
    const float* Wk   = (const float*)d_in[5];
    const float* bk   = (const float*)d_in[6];
    const float* Wq   = (const float*)d_in[7];
    const float* bq   = (const float*)d_in[8];
    const float* Wv   = (const float*)d_in[9];
    const float* bv   = (const float*)d_in[10];
    const float* Wo   = (const float*)d_in[11];
    const float* bo   = (const float*)d_in[12];
    const float* lng  = (const float*)d_in[13];
    const float* lnb  = (const float*)d_in[14];

    h16* Qh  = (h16*)d_ws;                   // B*N*16 h16   = 1 MB
    h16* Kh  = Qh + 524288;                  // 1 MB
    h16* VTh = Kh + 524288;                  // B*32*N h16   = 2 MB
    float* Wb = (float*)(VTh + 1048576);     // B*N f32      = 128 KB
    float* part = Wb + 32768;                // B*N*4*36 f32 = 18.9 MB
    float* out = (float*)d_out;

    proj_kernel<<<(BB*NN)/256, 256, 0, stream>>>(x, feat, dlw, Wk, bk, Wq, bq,
                                                 Wv, bv, Qh, Kh, VTh, Wb);
    attn_kernel<<<128*4*NSPLIT, 256, 0, stream>>>(Qh, Kh, VTh, adj, aw, part);
    combine_kernel<<<(BB*NN)/64, 256, 0, stream>>>(part, Wb, Wo, bo, lng, lnb, out);
}